// Round 1
// 139.471 us; speedup vs baseline: 1.0921x; 1.0921x over previous
//
#include <hip/hip_runtime.h>
#include <math.h>

#define Hh 128
#define Ww 128
#define HW (Hh*Ww)
#define Bn 4
#define Cn 64
#define On 64
#define KP 200                // LDS A-row stride (shorts): 192 data + 8 pad
#define OMP 66                // padded px stride for sOM (f16), 64 px
#define NBLK 1024             // dcn grid (half-row blocks)

typedef __attribute__((ext_vector_type(8))) short bf16x8;
typedef __attribute__((ext_vector_type(4))) float f32x4;
typedef __attribute__((ext_vector_type(4))) unsigned short u16x4;
typedef __attribute__((ext_vector_type(4))) short s16x4;

// fp32 -> bf16 round-to-nearest-even
static __device__ __forceinline__ unsigned short f2bf(float f) {
    unsigned u = __builtin_bit_cast(unsigned, f);
    u += 0x7FFFu + ((u >> 16) & 1u);
    return (unsigned short)(u >> 16);
}
static __device__ __forceinline__ float bf2f(unsigned short s) {
    unsigned u = ((unsigned)s) << 16;
    return __builtin_bit_cast(float, u);
}
static __device__ __forceinline__ short f2h(float f) {
    _Float16 h = (_Float16)f;
    return __builtin_bit_cast(short, h);
}
static __device__ __forceinline__ float h2f(short s) {
    return (float)__builtin_bit_cast(_Float16, s);
}

// workspace layout (bytes): xtb(8M) | conv(16M) | part(512K) | ss | owT | dwT
#define XTB_BYTES   ((size_t)Bn*HW*64*2)
#define CONV_BYTES  ((size_t)Bn*On*HW*4)
#define PART_BYTES  ((size_t)128*NBLK*4)

// ---------------------------------------------------------------------------
// Prep: blocks 0..511 = NCHW->NHWC bf16 transpose (one (b,h) row each);
//       blocks 512..727 = weight pack bf16 tap-major [o][tap][c].
// ---------------------------------------------------------------------------
__global__ __launch_bounds__(256) void prep_k(
    const float* __restrict__ x,  const float* __restrict__ ow,
    const float* __restrict__ dw, unsigned* __restrict__ xtb,
    short* __restrict__ owT,      short* __restrict__ dwT)
{
    int blk = blockIdx.x;
    int t = threadIdx.x;
    if (blk < 512) {
        int b = blk >> 7, h = blk & 127;
        __shared__ float sT[64 * 133];
        const float* xp = x + (size_t)b * Cn * HW + (size_t)h * Ww;
#pragma unroll
        for (int it = 0; it < 32; ++it) {
            int idx = t + 256 * it;        // c(6b) | w(7b)
            int c = idx >> 7, w = idx & 127;
            sT[c * 133 + w] = xp[(size_t)c * HW + w];
        }
        __syncthreads();
        unsigned* op = xtb + (size_t)blk * Ww * 32;   // 32 dwords (64 bf16)/px
#pragma unroll
        for (int it = 0; it < 16; ++it) {
            int idx = t + 256 * it;        // w(7b) | cp(5b)
            int w = idx >> 5, cp = idx & 31;
            unsigned lo = f2bf(sT[(2 * cp) * 133 + w]);
            unsigned hi = f2bf(sT[(2 * cp + 1) * 133 + w]);
            op[(size_t)w * 32 + cp] = lo | (hi << 16);
        }
    } else {
        int u = (blk - 512) * 4 + (t >> 6);   // 0..863
        int c = t & 63;
        if (u < 288) {
            int o = u / 9, kk = u % 9;
            float v = (o < 27) ? ow[(size_t)o * 576 + c * 9 + kk] : 0.0f;
            owT[(size_t)u * 64 + c] = (short)f2bf(v);
        } else {
            int u2 = u - 288;
            int o = u2 / 9, kk = u2 % 9;
            dwT[(size_t)u2 * 64 + c] = (short)f2bf(dw[(size_t)o * 576 + c * 9 + kk]);
        }
    }
}

// ---------------------------------------------------------------------------
// Fused: offset-conv GEMM -> per-thread bilinear prep -> sampling fill ->
// DCN GEMM -> conv store + BN stats partials (transposed part).
// Block = HALF-row (64 px; quarter-row R12 regressed dcn 76->91 us), grid
// 1024, XCD-swizzled. x is bf16 NHWC (dword = 2 channels).
// Phase-1 fill = pure dword copy, 2 px per wave-iter (no math).
// Phase-3 fill (this round): channel-PAIR per lane via dword gathers --
// halves global-load issue count (2304->1152/block) and loop overhead;
// pack via v_cvt_pk_bf16_f32 (RNE, numerically identical to f2bf pair).
// CRITICAL #1: no __launch_bounds__ min-waves arg (R3 spill disaster).
// CRITICAL #2: wave id readfirstlane'd (R4 divergent-uniform trap).
// MFMA 16x16x32 bf16 (validated R8-R12):
//   A lane=[m=l15][k=quad*8+j]; B lane=[k=quad*8+j][n=l15];
//   D lane=[row=quad*4+r][col=l15].
// LDS: sA 25600 + sOMh 3612 + prepIdx 4608 + prepW 4608 ~= 38.4 KB -> 4/CU.
// ---------------------------------------------------------------------------
__global__ __launch_bounds__(256) void dcn_fused_k(
    const unsigned* __restrict__ xtb, const short* __restrict__ owT,
    const float* __restrict__ ob,     const short* __restrict__ dwT,
    float* __restrict__ conv,         float* __restrict__ part)
{
    int raw  = blockIdx.x;
    int blk  = ((raw & 7) << 7) | (raw >> 3);   // b(2b) | h(7b) | half(1b)
    int half = blk & 1;
    int h    = (blk >> 1) & 127;
    int b    = blk >> 8;
    int px0  = half * 64;
    int t    = threadIdx.x;
    int lane = t & 63;
    int quad = lane >> 4;
    int l15  = lane & 15;
    int hl   = lane >> 5;          // half-wave index (px parity ph1 / unit ph3)
    int cl   = lane & 31;          // channel-pair index 0..31
    int w_s  = __builtin_amdgcn_readfirstlane(t >> 6);   // 0..3 (SGPR)

    __shared__ __align__(16) short sA[64 * KP];               // 25600 B (bf16)
    __shared__ __align__(16) short sOMh[27 * OMP + 12];       //  3612 B (f16)
    __shared__ __align__(16) unsigned short prepIdx[576 * 4]; //  4608 B
    __shared__ __align__(16) short prepW[576 * 4];            //  4608 B (f16)

    const unsigned* xbd = xtb + (size_t)b * HW * 32;               // dword view
    unsigned* sAd = (unsigned*)sA;                                 // row = 100 dw

    // ================= Phase 1: offset conv GEMM (M=64, N=32) ============
    int nt_o = w_s & 1;
    int mh   = w_s >> 1;
    int o_ow = nt_o * 16 + l15;
    f32x4 oacc[2] = {{0,0,0,0},{0,0,0,0}};

    for (int ck = 0; ck < 3; ++ck) {
        // ---- im2col fill: 96 px-pairs x 3 kkl; pure dword copy
#pragma unroll 4
        for (int pr = 0; pr < 24; ++pr) {
            int pair = pr * 4 + w_s;
            int kkl = pair >> 5, px2 = pair & 31;
            int px = px2 * 2 + hl;
            int yy = h + ck - 1;
            int xx = px0 + px + kkl - 1;
            bool valid = ((unsigned)yy < (unsigned)Hh) && ((unsigned)xx < (unsigned)Ww);
            unsigned v = valid ? xbd[(((size_t)yy << 7) + xx) * 32 + cl] : 0u;
            sAd[px * 100 + kkl * 32 + cl] = v;
        }
        __syncthreads();
#pragma unroll
        for (int ks = 0; ks < 6; ++ks) {
            int kk = ck * 3 + (ks >> 1);
            bf16x8 bfr = *(const bf16x8*)&owT[((size_t)o_ow * 9 + kk) * 64
                                             + (ks & 1) * 32 + quad * 8];
#pragma unroll
            for (int m2 = 0; m2 < 2; ++m2) {
                bf16x8 a = *(const bf16x8*)&sA[(mh * 32 + m2 * 16 + l15) * KP
                                               + ks * 32 + quad * 8];
                oacc[m2] = __builtin_amdgcn_mfma_f32_16x16x32_bf16(a, bfr, oacc[m2], 0, 0, 0);
            }
        }
        __syncthreads();
    }
    // ---- D -> sOMh (+bias), f16; px = (mh*2+m2)*16 + quad*4 + r
    if (o_ow < 27) {
        float bias = ob[o_ow];
#pragma unroll
        for (int m2 = 0; m2 < 2; ++m2) {
            int pxb = (mh * 2 + m2) * 16 + quad * 4;
#pragma unroll
            for (int r = 0; r < 4; ++r)
                sOMh[o_ow * OMP + pxb + r] = f2h(oacc[m2][r] + bias);
        }
    }
    __syncthreads();

    // ================= Phase 2: per-thread bilinear prep -> LDS ==========
    // 576 units = tap(9) x px(64); thread owns u = t, t+256, t+512(<576)
#pragma unroll
    for (int i = 0; i < 3; ++i) {
        int u = t + 256 * i;
        if (u < 576) {
            int kk = u >> 6, px = u & 63;
            float ox = h2f(sOMh[kk * OMP + px]);
            float oy = h2f(sOMh[(9 + kk) * OMP + px]);
            float mr = h2f(sOMh[(18 + kk) * OMP + px]);
            float m  = 1.0f / (1.0f + __expf(-mr));
            float py  = (float)(h - 1 + (kk / 3)) + oy;
            float pxf = (float)(px0 + px - 1 + (kk % 3)) + ox;
            float y0f = floorf(py), x0f = floorf(pxf);
            int y0 = (int)y0f, x0 = (int)x0f;
            float wy = py - y0f, wx = pxf - x0f;
#pragma unroll
            for (int dy = 0; dy < 2; ++dy) {
#pragma unroll
                for (int dx = 0; dx < 2; ++dx) {
                    int yi = y0 + dy, xi = x0 + dx;
                    bool valid = (yi >= 0) && (yi < Hh) && (xi >= 0) && (xi < Ww);
                    int yc = min(max(yi, 0), Hh - 1);
                    int xc = min(max(xi, 0), Ww - 1);
                    float wgt = (dy ? wy : 1.0f - wy) * (dx ? wx : 1.0f - wx);
                    prepIdx[u * 4 + dy * 2 + dx] = (unsigned short)(yc * Ww + xc);
                    prepW[u * 4 + dy * 2 + dx]   = f2h(valid ? (wgt * m) : 0.0f);
                }
            }
        }
    }
    __syncthreads();

    // ================= Phase 3: sampling fill + DCN GEMM (M=64, N=64) ====
    // Fill: 2 units per wave-iter. Lanes 0-31 -> unit base+0, lanes 32-63 ->
    // unit base+1; each lane owns a CHANNEL PAIR (one dword of NHWC bf16).
    // Per corner: 1 dword load (128 B/half-wave, coalesced), 2 free casts,
    // 2 FMA. Write: dword to sAd, halves land 100 dwords apart (bank+4,
    // 2-way = free). prepIdx/prepW reads: 2-address ds_read_b64 broadcast.
    int o_dw = w_s * 16 + l15;
    f32x4 acc[4] = {{0,0,0,0},{0,0,0,0},{0,0,0,0},{0,0,0,0}};

    for (int ck = 0; ck < 3; ++ck) {
#pragma unroll 4
        for (int uu = 0; uu < 24; ++uu) {
            int unit = (uu * 4 + w_s) * 2 + hl;  // 0..191 within ck
            int kkl = unit >> 6, px = unit & 63;
            int u = ck * 192 + unit;             // global unit id
            u16x4 pi = *(const u16x4*)&prepIdx[u * 4];   // 2-addr ds_read_b64
            s16x4 pw = *(const s16x4*)&prepW[u * 4];
            float v0 = 0.0f, v1 = 0.0f;
#pragma unroll
            for (int j = 0; j < 4; ++j) {
                unsigned d = xbd[(size_t)pi[j] * 32 + cl];    // 2 channels
                float wj = h2f(pw[j]);
                float clo = __builtin_bit_cast(float, d << 16);
                float chi = __builtin_bit_cast(float, d & 0xFFFF0000u);
                v0 += wj * clo;
                v1 += wj * chi;
            }
            unsigned pk;
            asm("v_cvt_pk_bf16_f32 %0, %1, %2" : "=v"(pk) : "v"(v0), "v"(v1));
            sAd[px * 100 + kkl * 32 + cl] = pk;
        }
        __syncthreads();
#pragma unroll
        for (int ks = 0; ks < 6; ++ks) {
            int kk = ck * 3 + (ks >> 1);
            bf16x8 bfr = *(const bf16x8*)&dwT[((size_t)o_dw * 9 + kk) * 64
                                              + (ks & 1) * 32 + quad * 8];
#pragma unroll
            for (int mt = 0; mt < 4; ++mt) {
                bf16x8 a = *(const bf16x8*)&sA[(mt * 16 + l15) * KP
                                               + ks * 32 + quad * 8];
                acc[mt] = __builtin_amdgcn_mfma_f32_16x16x32_bf16(a, bfr, acc[mt], 0, 0, 0);
            }
        }
        __syncthreads();
    }

    // ================= Phase 4: store conv + stats partials =================
#pragma unroll
    for (int mt = 0; mt < 4; ++mt) {
        size_t idx = ((size_t)b * On + o_dw) * HW + (size_t)h * Ww + px0 + mt * 16 + quad * 4;
        *(f32x4*)(conv + idx) = acc[mt];
    }
    float s1 = 0.0f, s2 = 0.0f;
#pragma unroll
    for (int mt = 0; mt < 4; ++mt) {
#pragma unroll
        for (int r = 0; r < 4; ++r) {
            float v = acc[mt][r];
            s1 += v;
            s2 += v * v;
        }
    }
    s1 += __shfl_down(s1, 32, 64);  s2 += __shfl_down(s2, 32, 64);
    s1 += __shfl_down(s1, 16, 64);  s2 += __shfl_down(s2, 16, 64);
    if (lane < 16) {
        part[(size_t)o_dw * NBLK + blk]        = s1;
        part[(size_t)(64 + o_dw) * NBLK + blk] = s2;
    }
}

// ---------------------------------------------------------------------------
// Stats reduce: part is [chan128][NBLK]. Block o sums channel o (sum) and
// 64+o (sumsq) coalesced -> ss[o], ss[64+o].
// ---------------------------------------------------------------------------
__global__ __launch_bounds__(256) void stats_k(
    const float* __restrict__ part, const float* __restrict__ gamma,
    const float* __restrict__ beta, float* __restrict__ ss)
{
    int o = blockIdx.x;
    int t = threadIdx.x;
    float s1 = 0.0f, s2 = 0.0f;
    for (int i = t; i < NBLK; i += 256) {
        s1 += part[(size_t)o * NBLK + i];
        s2 += part[(size_t)(64 + o) * NBLK + i];
    }
#pragma unroll
    for (int off = 32; off > 0; off >>= 1) {
        s1 += __shfl_down(s1, off, 64);
        s2 += __shfl_down(s2, off, 64);
    }
    __shared__ float r1[4], r2[4];
    if ((t & 63) == 0) { r1[t >> 6] = s1; r2[t >> 6] = s2; }
    __syncthreads();
    if (t == 0) {
        float S1 = r1[0] + r1[1] + r1[2] + r1[3];
        float S2 = r2[0] + r2[1] + r2[2] + r2[3];
        float n = (float)(Bn * HW);
        float mu = S1 / n;
        float var = S2 / n - mu * mu;
        float sc = gamma[o] * rsqrtf(var + 1e-5f);
        ss[o] = sc;
        ss[64 + o] = beta[o] - mu * sc;
    }
}

// ---------------------------------------------------------------------------
// BN + ReLU apply, float4
// ---------------------------------------------------------------------------
__global__ __launch_bounds__(256) void bnrelu_k(
    const float* __restrict__ conv, const float* __restrict__ ss,
    float* __restrict__ out)
{
    int i = blockIdx.x * blockDim.x + threadIdx.x;
    int ch = (i >> 12) & 63;
    float sc = ss[ch];
    float sh = ss[64 + ch];
    const float4* cv = (const float4*)conv;
    float4* ov = (float4*)out;
    float4 v = cv[i];
    v.x = fmaxf(v.x * sc + sh, 0.0f);
    v.y = fmaxf(v.y * sc + sh, 0.0f);
    v.z = fmaxf(v.z * sc + sh, 0.0f);
    v.w = fmaxf(v.w * sc + sh, 0.0f);
    ov[i] = v;
}

// ---------------------------------------------------------------------------
extern "C" void kernel_launch(void* const* d_in, const int* in_sizes, int n_in,
                              void* d_out, int out_size, void* d_ws, size_t ws_size,
                              hipStream_t stream)
{
    const float* x     = (const float*)d_in[0];
    const float* ow    = (const float*)d_in[1];
    const float* ob    = (const float*)d_in[2];
    const float* dw    = (const float*)d_in[3];
    // d_in[4] = dcn_b: cancels exactly under BN mean subtraction -> unused
    const float* gamma = (const float*)d_in[5];
    const float* beta  = (const float*)d_in[6];

    char* wsb = (char*)d_ws;
    unsigned* xtb = (unsigned*)wsb;
    float* conv = (float*)(wsb + XTB_BYTES);
    float* part = (float*)(wsb + XTB_BYTES + CONV_BYTES);
    float* ss   = (float*)(wsb + XTB_BYTES + CONV_BYTES + PART_BYTES);
    short* owT  = (short*)(wsb + XTB_BYTES + CONV_BYTES + PART_BYTES + 512);
    short* dwT  = owT + 288 * 64;

    prep_k     <<<dim3(728),  dim3(256), 0, stream>>>(x, ow, dw, xtb, owT, dwT);
    dcn_fused_k<<<dim3(NBLK), dim3(256), 0, stream>>>(xtb, owT, ob, dwT, conv, part);
    stats_k    <<<dim3(64),   dim3(256), 0, stream>>>(part, gamma, beta, ss);
    bnrelu_k   <<<dim3(Bn * On * HW / 4 / 256), dim3(256), 0, stream>>>(conv, ss, (float*)d_out);
}

// Round 2
// 136.819 us; speedup vs baseline: 1.1133x; 1.0194x over previous
//
#include <hip/hip_runtime.h>
#include <math.h>

#define Hh 128
#define Ww 128
#define HW (Hh*Ww)
#define Bn 4
#define Cn 64
#define On 64
#define KP 200                // LDS A-row stride (shorts): 192 data + 8 pad
                              // (must stay ==0 mod 8 for 16B-aligned ds_read_b128;
                              //  200 -> row stride 100 dw == 4 mod 32 banks -> 2-way max)
#define OMP 66                // padded px stride for sOM (f16), 64 px
#define NBLK 1024             // dcn grid (half-row blocks)

typedef __attribute__((ext_vector_type(8))) short bf16x8;
typedef __attribute__((ext_vector_type(4))) float f32x4;
typedef __attribute__((ext_vector_type(4))) unsigned short u16x4;

// fp32 -> bf16 round-to-nearest-even
static __device__ __forceinline__ unsigned short f2bf(float f) {
    unsigned u = __builtin_bit_cast(unsigned, f);
    u += 0x7FFFu + ((u >> 16) & 1u);
    return (unsigned short)(u >> 16);
}
static __device__ __forceinline__ short f2h(float f) {
    _Float16 h = (_Float16)f;
    return __builtin_bit_cast(short, h);
}
static __device__ __forceinline__ float h2f(short s) {
    return (float)__builtin_bit_cast(_Float16, s);
}

// workspace layout (bytes): xtb(8M) | conv(16M) | part(512K) | ss | owT | dwT
#define XTB_BYTES   ((size_t)Bn*HW*64*2)
#define CONV_BYTES  ((size_t)Bn*On*HW*4)
#define PART_BYTES  ((size_t)128*NBLK*4)

// ---------------------------------------------------------------------------
// Prep: blocks 0..511 = NCHW->NHWC bf16 transpose (one (b,h) row each);
//       blocks 512..727 = weight pack bf16 tap-major [o][tap][c].
// ---------------------------------------------------------------------------
__global__ __launch_bounds__(256) void prep_k(
    const float* __restrict__ x,  const float* __restrict__ ow,
    const float* __restrict__ dw, unsigned* __restrict__ xtb,
    short* __restrict__ owT,      short* __restrict__ dwT)
{
    int blk = blockIdx.x;
    int t = threadIdx.x;
    if (blk < 512) {
        int b = blk >> 7, h = blk & 127;
        __shared__ float sT[64 * 133];
        const float* xp = x + (size_t)b * Cn * HW + (size_t)h * Ww;
#pragma unroll
        for (int it = 0; it < 32; ++it) {
            int idx = t + 256 * it;        // c(6b) | w(7b)
            int c = idx >> 7, w = idx & 127;
            sT[c * 133 + w] = xp[(size_t)c * HW + w];
        }
        __syncthreads();
        unsigned* op = xtb + (size_t)blk * Ww * 32;   // 32 dwords (64 bf16)/px
#pragma unroll
        for (int it = 0; it < 16; ++it) {
            int idx = t + 256 * it;        // w(7b) | cp(5b)
            int w = idx >> 5, cp = idx & 31;
            unsigned lo = f2bf(sT[(2 * cp) * 133 + w]);
            unsigned hi = f2bf(sT[(2 * cp + 1) * 133 + w]);
            op[(size_t)w * 32 + cp] = lo | (hi << 16);
        }
    } else {
        int u = (blk - 512) * 4 + (t >> 6);   // 0..863
        int c = t & 63;
        if (u < 288) {
            int o = u / 9, kk = u % 9;
            float v = (o < 27) ? ow[(size_t)o * 576 + c * 9 + kk] : 0.0f;
            owT[(size_t)u * 64 + c] = (short)f2bf(v);
        } else {
            int u2 = u - 288;
            int o = u2 / 9, kk = u2 % 9;
            dwT[(size_t)u2 * 64 + c] = (short)f2bf(dw[(size_t)o * 576 + c * 9 + kk]);
        }
    }
}

// ---------------------------------------------------------------------------
// Fused: offset-conv GEMM -> per-thread bilinear prep -> sampling fill ->
// DCN GEMM -> conv store + BN stats partials (transposed part).
// Block = HALF-row (64 px), grid 1024, XCD-swizzled. x is bf16 NHWC.
// Phase-3 fill: channel-PAIR per lane via dword gathers (R1, validated).
// This round (R2):
//  * prep compaction: base idx + 4 precomputed f16 corner-product weights
//    (validity factorizes per-axis onto physical rows/cols ybase/ybase+1) ->
//    5 shorts/unit, fill does ONE addr chain + imm offsets instead of 4.
//  * sOMh aliased into sA (sA dead during phase 2) -> LDS 38912 -> 31360 B.
// CRITICAL #1: no __launch_bounds__ min-waves arg (R3 spill disaster).
// CRITICAL #2: wave id readfirstlane'd (R4 divergent-uniform trap).
// MFMA 16x16x32 bf16 (validated R8-R12):
//   A lane=[m=l15][k=quad*8+j]; B lane=[k=quad*8+j][n=l15];
//   D lane=[row=quad*4+r][col=l15].
// LDS: sA 25600 (sOMh 3588 aliased in) + prepQ 4608 + prepC 1152 = 31360 B.
// ---------------------------------------------------------------------------
__global__ __launch_bounds__(256) void dcn_fused_k(
    const unsigned* __restrict__ xtb, const short* __restrict__ owT,
    const float* __restrict__ ob,     const short* __restrict__ dwT,
    float* __restrict__ conv,         float* __restrict__ part)
{
    int raw  = blockIdx.x;
    int blk  = ((raw & 7) << 7) | (raw >> 3);   // b(2b) | h(7b) | half(1b)
    int half = blk & 1;
    int h    = (blk >> 1) & 127;
    int b    = blk >> 8;
    int px0  = half * 64;
    int t    = threadIdx.x;
    int lane = t & 63;
    int quad = lane >> 4;
    int l15  = lane & 15;
    int hl   = lane >> 5;          // half-wave index (px parity ph1 / unit ph3)
    int cl   = lane & 31;          // channel-pair index 0..31
    int w_s  = __builtin_amdgcn_readfirstlane(t >> 6);   // 0..3 (SGPR)

    __shared__ __align__(16) short sA[64 * KP];               // 25600 B (bf16)
    __shared__ __align__(16) unsigned short prepQ[576 * 4];   //  4608 B {idx,w00,w01,w10}
    __shared__ __align__(16) unsigned short prepC[576];       //  1152 B {w11}
    short* sOMh = sA;   // 27*OMP+12 = 1794 shorts, aliased (sA dead in phase 2)

    const unsigned* xbd = xtb + (size_t)b * HW * 32;               // dword view
    unsigned* sAd = (unsigned*)sA;                                 // row = 100 dw

    // ================= Phase 1: offset conv GEMM (M=64, N=32) ============
    int nt_o = w_s & 1;
    int mh   = w_s >> 1;
    int o_ow = nt_o * 16 + l15;
    f32x4 oacc[2] = {{0,0,0,0},{0,0,0,0}};

    for (int ck = 0; ck < 3; ++ck) {
        // ---- im2col fill: 96 px-pairs x 3 kkl; pure dword copy
#pragma unroll 4
        for (int pr = 0; pr < 24; ++pr) {
            int pair = pr * 4 + w_s;
            int kkl = pair >> 5, px2 = pair & 31;
            int px = px2 * 2 + hl;
            int yy = h + ck - 1;
            int xx = px0 + px + kkl - 1;
            bool valid = ((unsigned)yy < (unsigned)Hh) && ((unsigned)xx < (unsigned)Ww);
            unsigned v = valid ? xbd[(((size_t)yy << 7) + xx) * 32 + cl] : 0u;
            sAd[px * 100 + kkl * 32 + cl] = v;
        }
        __syncthreads();
#pragma unroll
        for (int ks = 0; ks < 6; ++ks) {
            int kk = ck * 3 + (ks >> 1);
            bf16x8 bfr = *(const bf16x8*)&owT[((size_t)o_ow * 9 + kk) * 64
                                             + (ks & 1) * 32 + quad * 8];
#pragma unroll
            for (int m2 = 0; m2 < 2; ++m2) {
                bf16x8 a = *(const bf16x8*)&sA[(mh * 32 + m2 * 16 + l15) * KP
                                               + ks * 32 + quad * 8];
                oacc[m2] = __builtin_amdgcn_mfma_f32_16x16x32_bf16(a, bfr, oacc[m2], 0, 0, 0);
            }
        }
        __syncthreads();
    }
    // ---- D -> sOMh (+bias), f16; px = (mh*2+m2)*16 + quad*4 + r
    // (sA is dead here: last chunk's MFMAs completed before the final sync)
    if (o_ow < 27) {
        float bias = ob[o_ow];
#pragma unroll
        for (int m2 = 0; m2 < 2; ++m2) {
            int pxb = (mh * 2 + m2) * 16 + quad * 4;
#pragma unroll
            for (int r = 0; r < 4; ++r)
                sOMh[o_ow * OMP + pxb + r] = f2h(oacc[m2][r] + bias);
        }
    }
    __syncthreads();

    // ================= Phase 2: per-thread bilinear prep -> LDS ==========
    // 576 units = tap(9) x px(64); thread owns u = t, t+256, t+512(<576).
    // Validity factorizes per-axis: contribution of physical rows
    // (yb, yb+1), yb = clamp(y0,0,126), with row weights selected so
    // out-of-range taps get weight 0; same for cols. Corner weight =
    // wr_dy * wc_dx (m folded into wr). Base idx = yb*128+xb; corners at
    // base {+0,+1,+128,+129} are always in-bounds.
#pragma unroll
    for (int i = 0; i < 3; ++i) {
        int u = t + 256 * i;
        if (u < 576) {
            int kk = u >> 6, px = u & 63;
            float ox = h2f((short)sOMh[kk * OMP + px]);
            float oy = h2f((short)sOMh[(9 + kk) * OMP + px]);
            float mr = h2f((short)sOMh[(18 + kk) * OMP + px]);
            float m  = 1.0f / (1.0f + __expf(-mr));
            float py  = (float)(h - 1 + (kk / 3)) + oy;
            float pxf = (float)(px0 + px - 1 + (kk % 3)) + ox;
            float y0f = floorf(py), x0f = floorf(pxf);
            int y0 = (int)y0f, x0 = (int)x0f;
            float wy = py - y0f, wx = pxf - x0f;
            int yb = min(max(y0, 0), Hh - 2);
            int xb = min(max(x0, 0), Ww - 2);
            float wr0 = (yb == y0) ? (1.0f - wy) : ((yb     == y0 + 1) ? wy : 0.0f);
            float wr1 = (yb == y0) ? wy          : ((yb + 1 == y0    ) ? (1.0f - wy) : 0.0f);
            float wc0 = (xb == x0) ? (1.0f - wx) : ((xb     == x0 + 1) ? wx : 0.0f);
            float wc1 = (xb == x0) ? wx          : ((xb + 1 == x0    ) ? (1.0f - wx) : 0.0f);
            wr0 *= m; wr1 *= m;
            prepQ[u * 4 + 0] = (unsigned short)(yb * Ww + xb);
            prepQ[u * 4 + 1] = (unsigned short)f2h(wr0 * wc0);
            prepQ[u * 4 + 2] = (unsigned short)f2h(wr0 * wc1);
            prepQ[u * 4 + 3] = (unsigned short)f2h(wr1 * wc0);
            prepC[u]         = (unsigned short)f2h(wr1 * wc1);
        }
    }
    __syncthreads();

    // ================= Phase 3: sampling fill + DCN GEMM (M=64, N=64) ====
    // Fill: 2 units per wave-iter (lanes 0-31 unit A, 32-63 unit B), each
    // lane owns a CHANNEL PAIR. Per unit: 1 b64 + 1 b16 broadcast ds_read,
    // ONE gather address chain (+imm 128 B for col+1, +1 add for row+1),
    // 4 dword loads, 8 FMA, v_cvt_pk_bf16_f32, 1 b32 LDS write.
    int o_dw = w_s * 16 + l15;
    f32x4 acc[4] = {{0,0,0,0},{0,0,0,0},{0,0,0,0},{0,0,0,0}};

    for (int ck = 0; ck < 3; ++ck) {
#pragma unroll 4
        for (int uu = 0; uu < 24; ++uu) {
            int unit = (uu * 4 + w_s) * 2 + hl;  // 0..191 within ck
            int kkl = unit >> 6, px = unit & 63;
            int u = ck * 192 + unit;             // global unit id
            u16x4 q = *(const u16x4*)&prepQ[u * 4];      // broadcast ds_read_b64
            float w00 = h2f((short)q[1]);
            float w01 = h2f((short)q[2]);
            float w10 = h2f((short)q[3]);
            float w11 = h2f((short)prepC[u]);            // broadcast ds_read_u16
            const unsigned* p0 = xbd + (size_t)q[0] * 32 + cl;
            unsigned d00 = p0[0];
            unsigned d01 = p0[32];       // col+1  (imm offset 128 B)
            unsigned d10 = p0[4096];     // row+1  (one extra addr)
            unsigned d11 = p0[4128];     // row+1, col+1 (imm offset)
            float v0 = w00 * __builtin_bit_cast(float, d00 << 16)
                     + w01 * __builtin_bit_cast(float, d01 << 16)
                     + w10 * __builtin_bit_cast(float, d10 << 16)
                     + w11 * __builtin_bit_cast(float, d11 << 16);
            float v1 = w00 * __builtin_bit_cast(float, d00 & 0xFFFF0000u)
                     + w01 * __builtin_bit_cast(float, d01 & 0xFFFF0000u)
                     + w10 * __builtin_bit_cast(float, d10 & 0xFFFF0000u)
                     + w11 * __builtin_bit_cast(float, d11 & 0xFFFF0000u);
            unsigned pk;
            asm("v_cvt_pk_bf16_f32 %0, %1, %2" : "=v"(pk) : "v"(v0), "v"(v1));
            sAd[px * 100 + kkl * 32 + cl] = pk;
        }
        __syncthreads();
#pragma unroll
        for (int ks = 0; ks < 6; ++ks) {
            int kk = ck * 3 + (ks >> 1);
            bf16x8 bfr = *(const bf16x8*)&dwT[((size_t)o_dw * 9 + kk) * 64
                                              + (ks & 1) * 32 + quad * 8];
#pragma unroll
            for (int mt = 0; mt < 4; ++mt) {
                bf16x8 a = *(const bf16x8*)&sA[(mt * 16 + l15) * KP
                                               + ks * 32 + quad * 8];
                acc[mt] = __builtin_amdgcn_mfma_f32_16x16x32_bf16(a, bfr, acc[mt], 0, 0, 0);
            }
        }
        __syncthreads();
    }

    // ================= Phase 4: store conv + stats partials =================
#pragma unroll
    for (int mt = 0; mt < 4; ++mt) {
        size_t idx = ((size_t)b * On + o_dw) * HW + (size_t)h * Ww + px0 + mt * 16 + quad * 4;
        *(f32x4*)(conv + idx) = acc[mt];
    }
    float s1 = 0.0f, s2 = 0.0f;
#pragma unroll
    for (int mt = 0; mt < 4; ++mt) {
#pragma unroll
        for (int r = 0; r < 4; ++r) {
            float v = acc[mt][r];
            s1 += v;
            s2 += v * v;
        }
    }
    s1 += __shfl_down(s1, 32, 64);  s2 += __shfl_down(s2, 32, 64);
    s1 += __shfl_down(s1, 16, 64);  s2 += __shfl_down(s2, 16, 64);
    if (lane < 16) {
        part[(size_t)o_dw * NBLK + blk]        = s1;
        part[(size_t)(64 + o_dw) * NBLK + blk] = s2;
    }
}

// ---------------------------------------------------------------------------
// Fused BN stats + apply + ReLU (replaces stats_k + bnrelu_k; one node less).
// Grid 1024: block = (q(2b) | b(2b) | o(6b)) -> o = idx&63, bq = idx>>6.
// Each block re-reduces its channel's part rows (8 KB, L2-hit) -> sc/sh,
// then applies BN+ReLU over a 4096-float slab of conv.
// ---------------------------------------------------------------------------
__global__ __launch_bounds__(256) void bnstats_k(
    const float* __restrict__ part, const float* __restrict__ gamma,
    const float* __restrict__ beta, const float* __restrict__ conv,
    float* __restrict__ out)
{
    int idx = blockIdx.x;
    int o  = idx & 63;
    int bq = idx >> 6;          // b(2b) | q(2b) interleaved: b = bq>>2, q = bq&3
    int t = threadIdx.x;
    float s1 = 0.0f, s2 = 0.0f;
#pragma unroll
    for (int i = 0; i < NBLK / 256; ++i) {
        int j = t + 256 * i;
        s1 += part[(size_t)o * NBLK + j];
        s2 += part[(size_t)(64 + o) * NBLK + j];
    }
#pragma unroll
    for (int off = 32; off > 0; off >>= 1) {
        s1 += __shfl_down(s1, off, 64);
        s2 += __shfl_down(s2, off, 64);
    }
    __shared__ float r1[4], r2[4];
    __shared__ float sc_s, sh_s;
    if ((t & 63) == 0) { r1[t >> 6] = s1; r2[t >> 6] = s2; }
    __syncthreads();
    if (t == 0) {
        float S1 = r1[0] + r1[1] + r1[2] + r1[3];
        float S2 = r2[0] + r2[1] + r2[2] + r2[3];
        float n = (float)(Bn * HW);
        float mu = S1 / n;
        float var = S2 / n - mu * mu;
        float sc = gamma[o] * rsqrtf(var + 1e-5f);
        sc_s = sc;
        sh_s = beta[o] - mu * sc;
    }
    __syncthreads();
    float sc = sc_s, sh = sh_s;
    size_t base = (((size_t)(bq >> 2) * On + o) * HW + (size_t)(bq & 3) * 4096) / 4;
    const float4* cv = (const float4*)conv + base;
    float4* ov = (float4*)out + base;
#pragma unroll
    for (int i = 0; i < 4; ++i) {
        float4 v = cv[t + 256 * i];
        v.x = fmaxf(v.x * sc + sh, 0.0f);
        v.y = fmaxf(v.y * sc + sh, 0.0f);
        v.z = fmaxf(v.z * sc + sh, 0.0f);
        v.w = fmaxf(v.w * sc + sh, 0.0f);
        ov[t + 256 * i] = v;
    }
}

// ---------------------------------------------------------------------------
extern "C" void kernel_launch(void* const* d_in, const int* in_sizes, int n_in,
                              void* d_out, int out_size, void* d_ws, size_t ws_size,
                              hipStream_t stream)
{
    const float* x     = (const float*)d_in[0];
    const float* ow    = (const float*)d_in[1];
    const float* ob    = (const float*)d_in[2];
    const float* dw    = (const float*)d_in[3];
    // d_in[4] = dcn_b: cancels exactly under BN mean subtraction -> unused
    const float* gamma = (const float*)d_in[5];
    const float* beta  = (const float*)d_in[6];

    char* wsb = (char*)d_ws;
    unsigned* xtb = (unsigned*)wsb;
    float* conv = (float*)(wsb + XTB_BYTES);
    float* part = (float*)(wsb + XTB_BYTES + CONV_BYTES);
    short* owT  = (short*)(wsb + XTB_BYTES + CONV_BYTES + PART_BYTES + 512);
    short* dwT  = owT + 288 * 64;

    prep_k     <<<dim3(728),  dim3(256), 0, stream>>>(x, ow, dw, xtb, owT, dwT);
    dcn_fused_k<<<dim3(NBLK), dim3(256), 0, stream>>>(xtb, owT, ob, dwT, conv, part);
    bnstats_k  <<<dim3(1024), dim3(256), 0, stream>>>(part, gamma, beta, conv, (float*)d_out);
}